// Round 2
// baseline (208.293 us; speedup 1.0000x reference)
//
#include <hip/hip_runtime.h>
#include <hip/hip_cooperative_groups.h>

namespace cg = cooperative_groups;

typedef float f4 __attribute__((ext_vector_type(4)));
typedef short bf16x8 __attribute__((ext_vector_type(8)));
typedef float f32x4 __attribute__((ext_vector_type(4)));

#define BB 32
#define CC 64
#define EE 8
#define HWX 4096   // 64*64 pixels
#define PXT 128    // pixels per tile (2 rows); fused block = 2 tiles (4 rows)
#define GPB 6400   // gp floats per batch: T 16*64 + C 16*4*64 + R 4*64 + Cor 16*64

// ---------------------------------------------------------------------------
// bf16 round-to-nearest-even helpers
// ---------------------------------------------------------------------------
__device__ __forceinline__ unsigned bf16r(float f) {
  unsigned u = __builtin_bit_cast(unsigned, f);
  u += 0x7FFFu + ((u >> 16) & 1u);
  return u >> 16;
}
__device__ __forceinline__ unsigned pack2(float a, float b) {
  return bf16r(a) | (bf16r(b) << 16);
}
union frag_cast { bf16x8 v; unsigned u[4]; };

// ---------------------------------------------------------------------------
// Fused cooperative kernel. Grid = (16 stripes, 32 batches), 256 thr.
// Stripe = rows 4pt..4pt+3 (2 tiles of 128 px).
// Phase A: load x tile->regs, accumulate per-channel stats
//          (T, edge-col sums, special-row sums, corners), pack bf16 frags.
// grid.sync()
// Phase B: reduce stats -> S[9] per channel -> logits (round-0-proven math),
//          softmax/top-1, MFMA expert mix on frags still in registers.
// MFMA layouts (HW-verified m89/m91):
//   A[m=lane&15][k=quad*8+j], B[k=quad*8+j][n=lane&15],
//   D: col(n)=lane&15, row(m)=quad*4+reg.
// Resident need: 2 blocks/CU (512 blocks). LDS ~11.6 KB, VGPR<=256 -> ample
// margin for cooperative-launch validation under any occupancy model.
// ---------------------------------------------------------------------------
__global__ __launch_bounds__(256, 2) void k_fused(
    const float* __restrict__ x, const float* __restrict__ gate_w,
    const float* __restrict__ gate_b, const float* __restrict__ expert_w,
    float* __restrict__ gp, float* __restrict__ out,
    float* __restrict__ ew_out) {
  __shared__ float sT[CC];           // stripe total per channel
  __shared__ float sC[4 * CC];       // edge-col sums (cols 0,1,62,63) x ch
  __shared__ float sR[4 * CC];       // special-row sums (rows 0,1,62,63) x ch
  __shared__ float sCor[16 * CC];    // corners [rslot*4+cslot][ch]
  __shared__ float rT[4 * CC];       // phase-B partials
  __shared__ float rC[16 * CC];
  __shared__ float gsh[EE];

  int t = threadIdx.x;
  int pt = blockIdx.x;               // 0..15 stripe
  int b  = blockIdx.y;
  int wave = t >> 6, lane = t & 63, l15 = lane & 15, quad = lane >> 4;

  if (t < CC) sT[t] = 0.f;
  sC[t] = 0.f;
  sR[t] = 0.f;
  __syncthreads();

  unsigned fbu[2][2][2][4];          // [tau][ss][kk][word]
  float tpart[16];
  #pragma unroll
  for (int v = 0; v < 16; v++) tpart[v] = 0.f;

  #pragma unroll
  for (int tau = 0; tau < 2; tau++) {
    // ---- x tile load: px = pt*256 + tau*128 + 32w + 16ss + l15 ----
    const float* Xb = x + (size_t)b * CC * HWX + pt * 256 + tau * 128 + 32 * wave;
    float xv[2][2][8];               // [ss][kk][j]; channel = kk*32 + quad*8 + j
    #pragma unroll
    for (int ss = 0; ss < 2; ss++) {
      const float* xp = Xb + ss * 16 + l15 + (size_t)(quad * 8) * HWX;
      #pragma unroll
      for (int kk = 0; kk < 2; kk++) {
        const float* xq = xp + (size_t)(kk * 32) * HWX;
        #pragma unroll
        for (int j = 0; j < 8; j++) xv[ss][kk][j] = xq[(size_t)j * HWX];
      }
    }

    // ---- per-channel stripe-total partials ----
    #pragma unroll
    for (int kk = 0; kk < 2; kk++)
      #pragma unroll
      for (int j = 0; j < 8; j++)
        tpart[kk * 8 + j] += xv[0][kk][j] + xv[1][kk][j];

    // ---- edge-column contributions (cols 0,1 from ss=0 even waves;
    //      cols 62,63 from ss=1 odd waves) ----
    if ((wave & 1) == 0) {
      int cls = (l15 == 0) ? 0 : (l15 == 1) ? 1 : -1;
      if (cls >= 0) {
        #pragma unroll
        for (int kk = 0; kk < 2; kk++)
          #pragma unroll
          for (int j = 0; j < 8; j++)
            atomicAdd(&sC[cls * CC + quad * 8 + kk * 32 + j], xv[0][kk][j]);
      }
    } else {
      int cls = (l15 == 14) ? 2 : (l15 == 15) ? 3 : -1;
      if (cls >= 0) {
        #pragma unroll
        for (int kk = 0; kk < 2; kk++)
          #pragma unroll
          for (int j = 0; j < 8; j++)
            atomicAdd(&sC[cls * CC + quad * 8 + kk * 32 + j], xv[1][kk][j]);
      }
    }

    // ---- special rows + corners: pt0/tau0 -> rows 0,1; pt15/tau1 -> 62,63 ----
    bool srow = (pt == 0 && tau == 0) || (pt == 15 && tau == 1);
    if (srow) {
      int slot = ((pt == 0) ? 0 : 2) + (wave >> 1);   // rows 0,1,62,63 -> 0..3
      float rp[16];
      #pragma unroll
      for (int kk = 0; kk < 2; kk++)
        #pragma unroll
        for (int j = 0; j < 8; j++)
          rp[kk * 8 + j] = xv[0][kk][j] + xv[1][kk][j];
      #pragma unroll
      for (int off = 8; off > 0; off >>= 1)
        #pragma unroll
        for (int v = 0; v < 16; v++) rp[v] += __shfl_down(rp[v], off, 16);
      if (l15 == 0) {
        #pragma unroll
        for (int kk = 0; kk < 2; kk++)
          #pragma unroll
          for (int j = 0; j < 8; j++)
            atomicAdd(&sR[slot * CC + quad * 8 + kk * 32 + j], rp[kk * 8 + j]);
      }
      if ((wave & 1) == 0) {
        int cls = (l15 == 0) ? 0 : (l15 == 1) ? 1 : -1;
        if (cls >= 0) {
          #pragma unroll
          for (int kk = 0; kk < 2; kk++)
            #pragma unroll
            for (int j = 0; j < 8; j++)
              sCor[(slot * 4 + cls) * CC + quad * 8 + kk * 32 + j] = xv[0][kk][j];
        }
      } else {
        int cls = (l15 == 14) ? 2 : (l15 == 15) ? 3 : -1;
        if (cls >= 0) {
          #pragma unroll
          for (int kk = 0; kk < 2; kk++)
            #pragma unroll
            for (int j = 0; j < 8; j++)
              sCor[(slot * 4 + cls) * CC + quad * 8 + kk * 32 + j] = xv[1][kk][j];
        }
      }
    }

    // ---- pack this tile's B-frags to bf16 (xv dead after this) ----
    #pragma unroll
    for (int ss = 0; ss < 2; ss++)
      #pragma unroll
      for (int kk = 0; kk < 2; kk++) {
        fbu[tau][ss][kk][0] = pack2(xv[ss][kk][0], xv[ss][kk][1]);
        fbu[tau][ss][kk][1] = pack2(xv[ss][kk][2], xv[ss][kk][3]);
        fbu[tau][ss][kk][2] = pack2(xv[ss][kk][4], xv[ss][kk][5]);
        fbu[tau][ss][kk][3] = pack2(xv[ss][kk][6], xv[ss][kk][7]);
      }
  }

  // ---- stripe-total reduce: over l15 within quad, then LDS ----
  #pragma unroll
  for (int off = 8; off > 0; off >>= 1)
    #pragma unroll
    for (int v = 0; v < 16; v++) tpart[v] += __shfl_down(tpart[v], off, 16);
  if (l15 == 0) {
    #pragma unroll
    for (int kk = 0; kk < 2; kk++)
      #pragma unroll
      for (int j = 0; j < 8; j++)
        atomicAdd(&sT[quad * 8 + kk * 32 + j], tpart[kk * 8 + j]);
  }
  __syncthreads();

  // ---- publish stats: gp[b] = {T[16][64], C[16][4][64], R[4][64], Cor[16][64]} ----
  float* gb = gp + (size_t)b * GPB;
  if (t < CC) gb[pt * CC + t] = sT[t];
  gb[1024 + pt * 256 + t] = sC[t];
  if (pt == 0) {
    if (t < 128) gb[5120 + t] = sR[t];
    gb[5376 + t] = sCor[t];
    gb[5376 + 256 + t] = sCor[256 + t];
  } else if (pt == 15) {
    if (t < 128) gb[5120 + 128 + t] = sR[128 + t];
    gb[5376 + 512 + t] = sCor[512 + t];
    gb[5376 + 768 + t] = sCor[768 + t];
  }
  __threadfence();                   // device-scope release for cross-XCD gp

  cg::this_grid().sync();

  // ---- phase B: gather stats for this b, assemble S[9], logits ----
  {
    int ch = t & 63, grp = t >> 6;
    float aT = 0.f, aC0 = 0.f, aC1 = 0.f, aC2 = 0.f, aC3 = 0.f;
    #pragma unroll
    for (int s0 = 0; s0 < 4; s0++) {
      int s = grp * 4 + s0;
      aT  += gb[s * CC + ch];
      aC0 += gb[1024 + s * 256 + 0 * CC + ch];
      aC1 += gb[1024 + s * 256 + 1 * CC + ch];
      aC2 += gb[1024 + s * 256 + 2 * CC + ch];
      aC3 += gb[1024 + s * 256 + 3 * CC + ch];
    }
    rT[grp * CC + ch] = aT;
    rC[(grp * 4 + 0) * CC + ch] = aC0;
    rC[(grp * 4 + 1) * CC + ch] = aC1;
    rC[(grp * 4 + 2) * CC + ch] = aC2;
    rC[(grp * 4 + 3) * CC + ch] = aC3;
  }
  __syncthreads();

  if (t < CC) {                      // wave 0, lane = channel
    float T = 0.f, C[4] = {0.f, 0.f, 0.f, 0.f};
    #pragma unroll
    for (int g2 = 0; g2 < 4; g2++) {
      T += rT[g2 * CC + t];
      #pragma unroll
      for (int c4 = 0; c4 < 4; c4++) C[c4] += rC[(g2 * 4 + c4) * CC + t];
    }
    float R[4], X[16];
    #pragma unroll
    for (int s = 0; s < 4; s++) R[s] = gb[5120 + s * CC + t];
    #pragma unroll
    for (int ci = 0; ci < 16; ci++) X[ci] = gb[5376 + ci * CC + t];
    const int EX[3][2] = {{2, 3}, {0, 3}, {0, 1}};
    float S[9];
    #pragma unroll
    for (int i = 0; i < 3; i++)
      #pragma unroll
      for (int j = 0; j < 3; j++) {
        float Re = R[EX[i][0]] + R[EX[i][1]];
        float Ce = C[EX[j][0]] + C[EX[j][1]];
        float Xc = X[EX[i][0] * 4 + EX[j][0]] + X[EX[i][0] * 4 + EX[j][1]]
                 + X[EX[i][1] * 4 + EX[j][0]] + X[EX[i][1] * 4 + EX[j][1]];
        S[i * 3 + j] = T - Re - Ce + Xc;
      }
    float le[EE];
    #pragma unroll
    for (int e = 0; e < EE; e++) {
      const float* gwe = gate_w + ((size_t)e * CC + t) * 9;
      float acc = 0.f;
      #pragma unroll
      for (int k = 0; k < 9; k++) acc += gwe[k] * S[k];
      le[e] = acc;
    }
    #pragma unroll
    for (int off = 32; off > 0; off >>= 1)
      #pragma unroll
      for (int e = 0; e < EE; e++) le[e] += __shfl_down(le[e], off, 64);
    if (t == 0) {
      #pragma unroll
      for (int e = 0; e < EE; e++) gsh[e] = le[e] + 3844.0f * gate_b[e];
    }
  }
  __syncthreads();

  // ---- every thread: top-1 softmax (block-uniform) ----
  float g[EE];
  #pragma unroll
  for (int e = 0; e < EE; e++) g[e] = gsh[e];
  int best = 0; float bg = g[0];
  #pragma unroll
  for (int e = 1; e < EE; e++) if (g[e] > bg) { bg = g[e]; best = e; }
  float s = 0.f;
  #pragma unroll
  for (int e = 0; e < EE; e++) s += __expf(g[e] - bg);
  float sc = 1.0f / s;
  if (pt == 0 && t < EE) ew_out[b * EE + t] = (t == best) ? sc : 0.f;

  // ---- A-frags from the selected expert ----
  const float* Wg = expert_w + (size_t)best * (CC * CC);
  bf16x8 afr[4][2];
  #pragma unroll
  for (int ft = 0; ft < 4; ft++) {
    const float* wrow = Wg + (ft * 16 + l15) * CC + quad * 8;
    #pragma unroll
    for (int kk = 0; kk < 2; kk++) {
      f4 w0 = *(const f4*)(wrow + kk * 32);
      f4 w1 = *(const f4*)(wrow + kk * 32 + 4);
      frag_cast fc;
      fc.u[0] = pack2(w0[0], w0[1]); fc.u[1] = pack2(w0[2], w0[3]);
      fc.u[2] = pack2(w1[0], w1[1]); fc.u[3] = pack2(w1[2], w1[3]);
      afr[ft][kk] = fc.v;
    }
  }

  // ---- MFMA + scaled store per tile ----
  #pragma unroll
  for (int tau = 0; tau < 2; tau++) {
    f32x4 acc[2][4] = {};
    #pragma unroll
    for (int ss = 0; ss < 2; ss++)
      #pragma unroll
      for (int kk = 0; kk < 2; kk++) {
        frag_cast fb;
        fb.u[0] = fbu[tau][ss][kk][0]; fb.u[1] = fbu[tau][ss][kk][1];
        fb.u[2] = fbu[tau][ss][kk][2]; fb.u[3] = fbu[tau][ss][kk][3];
        #pragma unroll
        for (int ft = 0; ft < 4; ft++)
          acc[ss][ft] = __builtin_amdgcn_mfma_f32_16x16x32_bf16(
              afr[ft][kk], fb.v, acc[ss][ft], 0, 0, 0);
      }
    #pragma unroll
    for (int ss = 0; ss < 2; ss++)
      #pragma unroll
      for (int ft = 0; ft < 4; ft++) {
        int f = ft * 16 + quad * 4;
        float* Og = out + ((size_t)(b * CC + f)) * HWX
                  + pt * 256 + tau * 128 + 32 * wave + ss * 16 + l15;
        #pragma unroll
        for (int r = 0; r < 4; r++)
          Og[(size_t)r * HWX] = sc * acc[ss][ft][r];
      }
  }
}

// ===========================================================================
// Fallback path: round-0 proven two-kernel pipeline (99.0 us, passing).
// ===========================================================================
__global__ __launch_bounds__(256) void k_gate_sums(
    const float* __restrict__ x, const float* __restrict__ gate_w,
    float* __restrict__ gpart) {
  __shared__ float sg[9];
  __shared__ float cor[4][4];
  __shared__ float sS[9];
  int t = threadIdx.x;
  int bc = blockIdx.x;
  int c = bc & 63;
  const float* plane = x + (size_t)bc * HWX;
  int h = t >> 2, q = t & 3;
  const f4* rp = (const f4*)(plane + h * 64 + q * 16);
  f4 a0 = rp[0], a1 = rp[1], a2 = rp[2], a3 = rp[3];
  float local = (a0[0]+a0[1]+a0[2]+a0[3]) + (a1[0]+a1[1]+a1[2]+a1[3])
              + (a2[0]+a2[1]+a2[2]+a2[3]) + (a3[0]+a3[1]+a3[2]+a3[3]);
  if (t < 9) sg[t] = 0.f;
  __syncthreads();

  bool special = (h < 2) || (h >= 62);
  int ridx = (h < 2) ? h : h - 60;

  float red = local;
  float c0v = (q == 0) ? a0[0] : 0.f;
  float c1v = (q == 0) ? a0[1] : 0.f;
  float c2v = (q == 3) ? a3[2] : 0.f;
  float c3v = (q == 3) ? a3[3] : 0.f;
  #pragma unroll
  for (int off = 32; off > 0; off >>= 1) {
    red += __shfl_down(red, off, 64);
    c0v += __shfl_down(c0v, off, 64);
    c1v += __shfl_down(c1v, off, 64);
    c2v += __shfl_down(c2v, off, 64);
    c3v += __shfl_down(c3v, off, 64);
  }
  if ((t & 63) == 0) {
    atomicAdd(&sg[0], red);
    atomicAdd(&sg[5], c0v); atomicAdd(&sg[6], c1v);
    atomicAdd(&sg[7], c2v); atomicAdd(&sg[8], c3v);
  }
  if (special) {
    atomicAdd(&sg[1 + ridx], local);
    if (q == 0) { cor[ridx][0] = a0[0]; cor[ridx][1] = a0[1]; }
    if (q == 3) { cor[ridx][2] = a3[2]; cor[ridx][3] = a3[3]; }
  }
  __syncthreads();

  if (t == 0) {
    const int EX[3][2] = {{2,3},{0,3},{0,1}};
    float T = sg[0];
    #pragma unroll
    for (int i = 0; i < 3; i++)
      #pragma unroll
      for (int j = 0; j < 3; j++) {
        float Re = sg[1 + EX[i][0]] + sg[1 + EX[i][1]];
        float Ce = sg[5 + EX[j][0]] + sg[5 + EX[j][1]];
        float Xc = cor[EX[i][0]][EX[j][0]] + cor[EX[i][0]][EX[j][1]]
                 + cor[EX[i][1]][EX[j][0]] + cor[EX[i][1]][EX[j][1]];
        sS[i * 3 + j] = T - Re - Ce + Xc;
      }
  }
  __syncthreads();

  if (t < EE) {
    const float* gw = gate_w + ((size_t)t * CC + c) * 9;
    float ge = 0.f;
    #pragma unroll
    for (int k = 0; k < 9; k++) ge += gw[k] * sS[k];
    int b = bc >> 6;
    gpart[b * (EE * CC) + t * CC + c] = ge;
  }
}

__global__ __launch_bounds__(256) void k_mix(
    const float* __restrict__ x, const float* __restrict__ expert_w,
    const float* __restrict__ gpart, const float* __restrict__ gate_b,
    float* __restrict__ out, float* __restrict__ ew_out) {
  __shared__ float gsh[EE];
  int t = threadIdx.x;
  int pt = blockIdx.x;
  int b  = blockIdx.y;
  int wave = t >> 6;
  int lane = t & 63;
  int l15  = lane & 15;
  int quad = lane >> 4;

  const float* Xb = x + (size_t)b * CC * HWX + pt * PXT + 32 * wave;
  float xv[2][2][8];
  #pragma unroll
  for (int ss = 0; ss < 2; ss++) {
    const float* xp = Xb + ss * 16 + l15 + (size_t)(quad * 8) * HWX;
    #pragma unroll
    for (int kk = 0; kk < 2; kk++) {
      const float* xq = xp + (size_t)(kk * 32) * HWX;
      #pragma unroll
      for (int j = 0; j < 8; j++) xv[ss][kk][j] = xq[(size_t)j * HWX];
    }
  }

  {
    int e = t >> 5, j = t & 31;
    const float* gp = gpart + b * (EE * CC) + e * CC;
    float gval = gp[j] + gp[j + 32];
    #pragma unroll
    for (int off = 16; off > 0; off >>= 1) gval += __shfl_down(gval, off, 32);
    if (j == 0) gsh[e] = gval + 3844.0f * gate_b[e];
  }
  __syncthreads();

  float g[EE];
  #pragma unroll
  for (int e = 0; e < EE; e++) g[e] = gsh[e];
  int best = 0; float bg = g[0];
  #pragma unroll
  for (int e = 1; e < EE; e++) if (g[e] > bg) { bg = g[e]; best = e; }
  float s = 0.f;
  #pragma unroll
  for (int e = 0; e < EE; e++) s += __expf(g[e] - bg);
  float sc = 1.0f / s;
  if (pt == 0 && t < EE) ew_out[b * EE + t] = (t == best) ? sc : 0.f;

  const float* Wg = expert_w + (size_t)best * (CC * CC);
  bf16x8 afr[4][2];
  #pragma unroll
  for (int ft = 0; ft < 4; ft++) {
    const float* wrow = Wg + (ft * 16 + l15) * CC + quad * 8;
    #pragma unroll
    for (int kk = 0; kk < 2; kk++) {
      f4 w0 = *(const f4*)(wrow + kk * 32);
      f4 w1 = *(const f4*)(wrow + kk * 32 + 4);
      frag_cast fc;
      fc.u[0] = pack2(w0[0], w0[1]); fc.u[1] = pack2(w0[2], w0[3]);
      fc.u[2] = pack2(w1[0], w1[1]); fc.u[3] = pack2(w1[2], w1[3]);
      afr[ft][kk] = fc.v;
    }
  }

  f32x4 acc[2][4] = {};
  #pragma unroll
  for (int ss = 0; ss < 2; ss++) {
    #pragma unroll
    for (int kk = 0; kk < 2; kk++) {
      frag_cast fb;
      fb.u[0] = pack2(xv[ss][kk][0], xv[ss][kk][1]);
      fb.u[1] = pack2(xv[ss][kk][2], xv[ss][kk][3]);
      fb.u[2] = pack2(xv[ss][kk][4], xv[ss][kk][5]);
      fb.u[3] = pack2(xv[ss][kk][6], xv[ss][kk][7]);
      #pragma unroll
      for (int ft = 0; ft < 4; ft++)
        acc[ss][ft] = __builtin_amdgcn_mfma_f32_16x16x32_bf16(
            afr[ft][kk], fb.v, acc[ss][ft], 0, 0, 0);
    }
  }

  #pragma unroll
  for (int ss = 0; ss < 2; ss++) {
    #pragma unroll
    for (int ft = 0; ft < 4; ft++) {
      int f = ft * 16 + quad * 4;
      float* Og = out + ((size_t)(b * CC + f)) * HWX
                + pt * PXT + 32 * wave + ss * 16 + l15;
      #pragma unroll
      for (int r = 0; r < 4; r++)
        Og[(size_t)r * HWX] = sc * acc[ss][ft][r];
    }
  }
}

// ---------------------------------------------------------------------------
extern "C" void kernel_launch(void* const* d_in, const int* in_sizes, int n_in,
                              void* d_out, int out_size, void* d_ws, size_t ws_size,
                              hipStream_t stream) {
  const float* x        = (const float*)d_in[0];   // [32,64,64,64]
  const float* gate_w   = (const float*)d_in[1];   // [8,64,3,3]
  const float* gate_b   = (const float*)d_in[2];   // [8]
  const float* expert_w = (const float*)d_in[3];   // [8,64,64]
  float* out = (float*)d_out;                      // [32,64,64,64] then [32,8]
  float* ew_out = out + (size_t)BB * CC * HWX;
  float* gp = (float*)d_ws;                        // stats buffer (coop) / gpart (fallback)

  void* kargs[] = {(void*)&x, (void*)&gate_w, (void*)&gate_b, (void*)&expert_w,
                   (void*)&gp, (void*)&out, (void*)&ew_out};
  hipError_t err = hipLaunchCooperativeKernel((void*)k_fused, dim3(16, BB),
                                              dim3(256), kargs, 0, stream);
  if (err != hipSuccess) {
    // proven round-0 path: gating partials then mix
    k_gate_sums<<<BB * CC, 256, 0, stream>>>(x, gate_w, gp);
    k_mix<<<dim3(HWX / PXT, BB), 256, 0, stream>>>(x, expert_w, gp, gate_b,
                                                   out, ew_out);
  }
}

// Round 3
// 99.568 us; speedup vs baseline: 2.0920x; 2.0920x over previous
//
#include <hip/hip_runtime.h>

typedef float f4 __attribute__((ext_vector_type(4)));
typedef short bf16x8 __attribute__((ext_vector_type(8)));
typedef float f32x4 __attribute__((ext_vector_type(4)));

#define BB 32
#define CC 64
#define EE 8
#define HWX 4096   // 64*64 pixels
#define PXT 128    // pixels per mix block

// ---------------------------------------------------------------------------
// bf16 round-to-nearest-even helpers
// ---------------------------------------------------------------------------
__device__ __forceinline__ unsigned bf16r(float f) {
  unsigned u = __builtin_bit_cast(unsigned, f);
  u += 0x7FFFu + ((u >> 16) & 1u);
  return u >> 16;
}
__device__ __forceinline__ unsigned pack2(float a, float b) {
  return bf16r(a) | (bf16r(b) << 16);
}
union frag_cast { bf16x8 v; unsigned u[4]; };

// ---------------------------------------------------------------------------
// NOTE (round-2 lesson): a fully-fused cooperative version of this pipeline
// was measured at 117 us/dispatch (vs ~15 us for the two kernels below).
// Cooperative co-residency caps the grid at 8 waves/CU, which cannot hide
// the strided x-load latency (hbm 469 GB/s, VALUBusy 2.9%). The grid-wide
// gating dependency is best served by two launches: kernel B's x re-read is
// L3-resident (33.5 MB << 256 MB Infinity Cache) and nearly free.
// ---------------------------------------------------------------------------

// ---------------------------------------------------------------------------
// Kernel A: per-(b,c) plane reductions -> per-c gating partials.
// gpart[b][e][c] = sum_{i,j} gw[e,c,i,j] * S[b,c,i,j]
// S[i,j] = T - excludedRows(i) - excludedCols(j) + corners(i,j)
// ---------------------------------------------------------------------------
__global__ __launch_bounds__(256) void k_gate_sums(
    const float* __restrict__ x, const float* __restrict__ gate_w,
    float* __restrict__ gpart) {
  __shared__ float sg[9];       // [T, r0,r1,r62,r63, c0,c1,c62,c63]
  __shared__ float cor[4][4];   // corner cells, rows/cols in {0,1,62,63}
  __shared__ float sS[9];       // the 9 window sums S[i*3+j]
  int t = threadIdx.x;
  int bc = blockIdx.x;          // b*64 + c
  int c = bc & 63;
  const float* plane = x + (size_t)bc * HWX;
  int h = t >> 2, q = t & 3;    // row h (0..63), quarter q (16 floats each)
  const f4* rp = (const f4*)(plane + h * 64 + q * 16);
  f4 a0 = rp[0], a1 = rp[1], a2 = rp[2], a3 = rp[3];
  float local = (a0[0]+a0[1]+a0[2]+a0[3]) + (a1[0]+a1[1]+a1[2]+a1[3])
              + (a2[0]+a2[1]+a2[2]+a2[3]) + (a3[0]+a3[1]+a3[2]+a3[3]);
  if (t < 9) sg[t] = 0.f;
  __syncthreads();

  bool special = (h < 2) || (h >= 62);
  int ridx = (h < 2) ? h : h - 60;   // 0,1,62,63 -> 0,1,2,3

  // ---- wave-level reductions: total + 4 column sums, 5 atomics per wave ----
  float red = local;
  float c0v = (q == 0) ? a0[0] : 0.f;   // col 0
  float c1v = (q == 0) ? a0[1] : 0.f;   // col 1
  float c2v = (q == 3) ? a3[2] : 0.f;   // col 62
  float c3v = (q == 3) ? a3[3] : 0.f;   // col 63
  #pragma unroll
  for (int off = 32; off > 0; off >>= 1) {
    red += __shfl_down(red, off, 64);
    c0v += __shfl_down(c0v, off, 64);
    c1v += __shfl_down(c1v, off, 64);
    c2v += __shfl_down(c2v, off, 64);
    c3v += __shfl_down(c3v, off, 64);
  }
  if ((t & 63) == 0) {
    atomicAdd(&sg[0], red);
    atomicAdd(&sg[5], c0v); atomicAdd(&sg[6], c1v);
    atomicAdd(&sg[7], c2v); atomicAdd(&sg[8], c3v);
  }

  if (special) {
    atomicAdd(&sg[1 + ridx], local);                     // full-row sums
    if (q == 0) { cor[ridx][0] = a0[0]; cor[ridx][1] = a0[1]; }
    if (q == 3) { cor[ridx][2] = a3[2]; cor[ridx][3] = a3[3]; }
  }
  __syncthreads();

  if (t == 0) {
    const int EX[3][2] = {{2,3},{0,3},{0,1}};  // excluded indices per offset
    float T = sg[0];
    #pragma unroll
    for (int i = 0; i < 3; i++)
      #pragma unroll
      for (int j = 0; j < 3; j++) {
        float Re = sg[1 + EX[i][0]] + sg[1 + EX[i][1]];
        float Ce = sg[5 + EX[j][0]] + sg[5 + EX[j][1]];
        float Xc = cor[EX[i][0]][EX[j][0]] + cor[EX[i][0]][EX[j][1]]
                 + cor[EX[i][1]][EX[j][0]] + cor[EX[i][1]][EX[j][1]];
        sS[i * 3 + j] = T - Re - Ce + Xc;
      }
  }
  __syncthreads();

  if (t < EE) {
    const float* gw = gate_w + ((size_t)t * CC + c) * 9;
    float ge = 0.f;
    #pragma unroll
    for (int k = 0; k < 9; k++) ge += gw[k] * sS[k];
    int b = bc >> 6;
    gpart[b * (EE * CC) + t * CC + c] = ge;   // direct store, no atomic
  }
}

// ---------------------------------------------------------------------------
// Kernel B: gating reduce + softmax/top-1 + MFMA expert 1x1-conv mix.
// Block: (pt, b) = one batch, 128 px. 4 waves; wave w owns px [32w, 32w+32).
// x-loads hoisted to the top so their latency overlaps the gating reduce.
// MFMA layouts (HW-verified m89/m91/m120):
//   A[m=lane&15][k=quad*8+j], B[k=quad*8+j][n=lane&15],
//   D: col(n)=lane&15, row(m)=quad*4+reg.
// ---------------------------------------------------------------------------
__global__ __launch_bounds__(256) void k_mix(
    const float* __restrict__ x, const float* __restrict__ expert_w,
    const float* __restrict__ gpart, const float* __restrict__ gate_b,
    float* __restrict__ out, float* __restrict__ ew_out) {
  __shared__ float gsh[EE];
  int t = threadIdx.x;
  int pt = blockIdx.x;            // 0..31 pixel tile (128 px)
  int b  = blockIdx.y;
  int wave = t >> 6;
  int lane = t & 63;
  int l15  = lane & 15;
  int quad = lane >> 4;

  // ---- hoisted B-operand loads (independent of gating result) ----
  const float* Xb = x + (size_t)b * CC * HWX + pt * PXT + 32 * wave;
  float xv[2][2][8];              // [ss][kk][j]; channel = kk*32 + quad*8 + j
  #pragma unroll
  for (int ss = 0; ss < 2; ss++) {
    const float* xp = Xb + ss * 16 + l15 + (size_t)(quad * 8) * HWX;
    #pragma unroll
    for (int kk = 0; kk < 2; kk++) {
      const float* xq = xp + (size_t)(kk * 32) * HWX;
      #pragma unroll
      for (int j = 0; j < 8; j++) xv[ss][kk][j] = xq[(size_t)j * HWX];
    }
  }

  // ---- gating reduction: 8 experts x 32 lanes ----
  {
    int e = t >> 5, j = t & 31;
    const float* gp = gpart + b * (EE * CC) + e * CC;
    float gval = gp[j] + gp[j + 32];
    #pragma unroll
    for (int off = 16; off > 0; off >>= 1) gval += __shfl_down(gval, off, 32);
    if (j == 0) gsh[e] = gval + 3844.0f * gate_b[e];
  }
  __syncthreads();

  // ---- every thread: top-1 softmax (block-uniform result) ----
  float g[EE];
  #pragma unroll
  for (int e = 0; e < EE; e++) g[e] = gsh[e];
  int best = 0; float bg = g[0];
  #pragma unroll
  for (int e = 1; e < EE; e++) if (g[e] > bg) { bg = g[e]; best = e; }
  float s = 0.f;
  #pragma unroll
  for (int e = 0; e < EE; e++) s += __expf(g[e] - bg);
  float sc = 1.0f / s;            // top-1 softmax prob
  if (pt == 0 && t < EE) ew_out[b * EE + t] = (t == best) ? sc : 0.f;

  // ---- A-frags: W[best][f0+l15][k0+quad*8+j], 4 f-tiles x 2 k0 ----
  const float* Wg = expert_w + (size_t)best * (CC * CC);
  bf16x8 afr[4][2];
  #pragma unroll
  for (int ft = 0; ft < 4; ft++) {
    const float* wrow = Wg + (ft * 16 + l15) * CC + quad * 8;
    #pragma unroll
    for (int kk = 0; kk < 2; kk++) {
      f4 w0 = *(const f4*)(wrow + kk * 32);
      f4 w1 = *(const f4*)(wrow + kk * 32 + 4);
      frag_cast fc;
      fc.u[0] = pack2(w0[0], w0[1]); fc.u[1] = pack2(w0[2], w0[3]);
      fc.u[2] = pack2(w1[0], w1[1]); fc.u[3] = pack2(w1[2], w1[3]);
      afr[ft][kk] = fc.v;
    }
  }

  // ---- pack B-frags + MFMA ----
  f32x4 acc[2][4] = {};           // [ss][ft]
  #pragma unroll
  for (int ss = 0; ss < 2; ss++) {
    #pragma unroll
    for (int kk = 0; kk < 2; kk++) {
      frag_cast fb;
      fb.u[0] = pack2(xv[ss][kk][0], xv[ss][kk][1]);
      fb.u[1] = pack2(xv[ss][kk][2], xv[ss][kk][3]);
      fb.u[2] = pack2(xv[ss][kk][4], xv[ss][kk][5]);
      fb.u[3] = pack2(xv[ss][kk][6], xv[ss][kk][7]);
      #pragma unroll
      for (int ft = 0; ft < 4; ft++)
        acc[ss][ft] = __builtin_amdgcn_mfma_f32_16x16x32_bf16(
            afr[ft][kk], fb.v, acc[ss][ft], 0, 0, 0);
    }
  }

  // ---- scaled store: f = 16*ft + quad*4 + r, px = pt*128+32w+16s+l15 ----
  #pragma unroll
  for (int ss = 0; ss < 2; ss++) {
    #pragma unroll
    for (int ft = 0; ft < 4; ft++) {
      int f = ft * 16 + quad * 4;
      float* Og = out + ((size_t)(b * CC + f)) * HWX
                + pt * PXT + 32 * wave + ss * 16 + l15;
      #pragma unroll
      for (int r = 0; r < 4; r++)
        Og[(size_t)r * HWX] = sc * acc[ss][ft][r];
    }
  }
}

// ---------------------------------------------------------------------------
extern "C" void kernel_launch(void* const* d_in, const int* in_sizes, int n_in,
                              void* d_out, int out_size, void* d_ws, size_t ws_size,
                              hipStream_t stream) {
  const float* x        = (const float*)d_in[0];   // [32,64,64,64]
  const float* gate_w   = (const float*)d_in[1];   // [8,64,3,3]
  const float* gate_b   = (const float*)d_in[2];   // [8]
  const float* expert_w = (const float*)d_in[3];   // [8,64,64]
  float* out = (float*)d_out;                      // [32,64,64,64] then [32,8]
  float* ew_out = out + (size_t)BB * CC * HWX;

  float* gpart = (float*)d_ws;   // [32][8][64] partials, fully written by kA

  k_gate_sums<<<BB * CC, 256, 0, stream>>>(x, gate_w, gpart);
  k_mix<<<dim3(HWX / PXT, BB), 256, 0, stream>>>(x, expert_w, gpart, gate_b,
                                                 out, ew_out);
}